// Round 11
// baseline (35.322 us; speedup 1.0000x reference)
//
#include <hip/hip_runtime.h>
#include <hip/hip_fp16.h>
#include <math.h>

#define D_DET 512
#define N_ANG 180
#define S_IMG 512
#define NPIX  (S_IMG * S_IMG)
#define T_MAX 63                 // ramp tap truncation

typedef _Float16 half2v __attribute__((ext_vector_type(2)));

__device__ __constant__ float kPI = 3.14159265358979323846f;

__device__ __forceinline__ half2v pack_weights(float a, float b) {
    return __builtin_bit_cast(half2v, __builtin_amdgcn_cvt_pkrtz(a, b));
}

// ---------------------------------------------------------------------------
// Stage 1: ramp filter, truncated symmetric convolution.
//   xf[d] = 0.5*r[d] + sum_{t odd,<=63} h(t)*(r[d-t]+r[d+t]), h(t)=-2/(pi t)^2
// Output: OVERLAPPED quad table (16B, 16B-aligned):
//   quad[a*512+k] = (pk(f0[k],f0[k+1]), pk(f1[k],f1[k+1]),
//                    pk(f0[k+1],f0[k+2]), pk(f1[k+1],f1[k+2]))
// with f[512]=f[513]=0. Any lerp window with base in {k, k+1} is served by
// ONE aligned dwordx4. Grid: 360 blocks = (angle, bc) x 512 threads.
// ---------------------------------------------------------------------------
__global__ __launch_bounds__(512) void ramp_filter_kernel(
    const float* __restrict__ x, uint4* __restrict__ xfq) {
    __shared__ float rp[640];            // [0,64)=0, [64,576)=row, [576,640)=0
    __shared__ float xf[D_DET + 2];

    const int a  = blockIdx.x >> 1;
    const int bc = blockIdx.x & 1;
    const int d  = threadIdx.x;

    if (d < 64)   rp[d] = 0.0f;
    if (d >= 448) rp[d + 128] = 0.0f;
    rp[64 + d] = x[(bc * D_DET + d) * N_ANG + a];
    if (d == 0) { xf[D_DET] = 0.0f; xf[D_DET + 1] = 0.0f; }
    __syncthreads();

    constexpr float PI_ = 3.14159265358979323846f;
    const float* rm = &rp[64 + d];
    float acc = 0.5f * rm[0];
    #pragma unroll
    for (int k = 0; k < (T_MAX + 1) / 2; ++k) {
        const int   t = 2 * k + 1;
        const float h = -2.0f / (PI_ * PI_ * (float)(t * t));   // literal
        acc = fmaf(rm[-t] + rm[t], h, acc);
    }
    xf[d] = acc;
    __syncthreads();

    const unsigned v0 = __half_as_ushort(__float2half_rn(xf[d]));
    const unsigned v1 = __half_as_ushort(__float2half_rn(xf[d + 1]));
    const unsigned v2 = __half_as_ushort(__float2half_rn(xf[d + 2]));
    unsigned* qq = (unsigned*)(xfq + a * D_DET + d);
    qq[bc]     = (v1 << 16) | v0;        // values (k, k+1)
    qq[2 + bc] = (v2 << 16) | v1;        // values (k+1, k+2)
}

// ---------------------------------------------------------------------------
// Stage 2: backprojection, j-PAIR threads: ONE dwordx4 gather per angle
// serves 2 adjacent-j pixels x both images. Offsets for BOTH pixels are
// derived from the shared quad base k = floor(min(pcA,pcB)):
//   off = pc - k in [0, 2.0002); sel = off>=1 picks the shifted sub-window;
//   w = off - sel. Weight/window consistent by construction -> immune to
// the fp32-rounding case where per-pixel floors differ by 2 (R10 bug).
// Wave = 16j x 8i compact patch. Grid: 1024 blocks x 128 threads.
// ---------------------------------------------------------------------------
__global__ __launch_bounds__(128) void backproj_kernel(
    const uint4* __restrict__ xfq, float* __restrict__ out) {
    __shared__ float2 trig[N_ANG];       // (cos*255.5, sin*255.5)
    const int tid = threadIdx.x;
    {
        float th = (float)tid * (kPI / 180.0f);
        float s, c;
        sincosf(th, &s, &c);
        trig[tid] = make_float2(c * 255.5f, s * 255.5f);   // 0..127
    }
    if (tid + 128 < N_ANG) {                               // 128..179
        float th = (float)(tid + 128) * (kPI / 180.0f);
        float s, c;
        sincosf(th, &s, &c);
        trig[tid + 128] = make_float2(c * 255.5f, s * 255.5f);
    }
    __syncthreads();

    const int bi   = blockIdx.x >> 4;    // 64 i-tiles of 8
    const int bj   = blockIdx.x & 15;    // 16 j-tiles of 32
    const int w    = tid >> 6;
    const int lane = tid & 63;
    const int jp   = (bj << 5) + (w << 4) + ((lane & 7) << 1);  // even j
    const int i    = (bi << 3) + (lane >> 3);

    const float xA = (float)jp * (2.0f / 511.0f) - 1.0f;
    const float xB = (float)(jp + 1) * (2.0f / 511.0f) - 1.0f;
    const float yP = (float)i * (2.0f / 511.0f) - 1.0f;
    const float mA = xA * xA + yP * yP;
    const float mB = xB * xB + yP * yP;
    const int  p   = i * S_IMG + jp;

    if (!__any((mA <= 1.0f) || (mB <= 1.0f))) {   // whole 16x8 patch outside
        *(float2*)(out + p)        = make_float2(0.0f, 0.0f);
        *(float2*)(out + NPIX + p) = make_float2(0.0f, 0.0f);
        return;
    }

    float a0A = 0.0f, a1A = 0.0f, a0B = 0.0f, a1B = 0.0f;
    #pragma unroll 4
    for (int a = 0; a < N_ANG; ++a) {
        float2 t  = trig[a];
        float by  = fmaf(yP, -t.y, 255.5f);
        float pcA = fminf(fmaxf(fmaf(xA, t.x, by), 0.0f), 511.0f);  // med3
        float pcB = fminf(fmaxf(fmaf(xB, t.x, by), 0.0f), 511.0f);
        float fm  = floorf(fminf(pcA, pcB));
        int   k   = (int)fm;
        uint4 g   = xfq[(a << 9) + k];
        float offA = pcA - fm;           // in [0, 2.0002)
        float offB = pcB - fm;
        bool  sA  = offA >= 1.0f;
        bool  sB  = offB >= 1.0f;
        float wA  = sA ? offA - 1.0f : offA;
        float wB  = sB ? offB - 1.0f : offB;
        half2v hA = pack_weights(1.0f - wA, wA);
        half2v hB = pack_weights(1.0f - wB, wB);
        unsigned gA0 = sA ? g.z : g.x;   // image-0 pair for A's sub-window
        unsigned gA1 = sA ? g.w : g.y;   // image-1 pair
        unsigned gB0 = sB ? g.z : g.x;
        unsigned gB1 = sB ? g.w : g.y;
        a0A = __builtin_amdgcn_fdot2(hA, __builtin_bit_cast(half2v, gA0), a0A, false);
        a1A = __builtin_amdgcn_fdot2(hA, __builtin_bit_cast(half2v, gA1), a1A, false);
        a0B = __builtin_amdgcn_fdot2(hB, __builtin_bit_cast(half2v, gB0), a0B, false);
        a1B = __builtin_amdgcn_fdot2(hB, __builtin_bit_cast(half2v, gB1), a1B, false);
    }

    const float scale = kPI / (2.0f * (float)N_ANG);
    const float sAo = (mA <= 1.0f) ? scale : 0.0f;
    const float sBo = (mB <= 1.0f) ? scale : 0.0f;
    *(float2*)(out + p)        = make_float2(a0A * sAo, a0B * sBo);
    *(float2*)(out + NPIX + p) = make_float2(a1A * sAo, a1B * sBo);
}

// ---------------------------------------------------------------------------
extern "C" void kernel_launch(void* const* d_in, const int* in_sizes, int n_in,
                              void* d_out, int out_size, void* d_ws, size_t ws_size,
                              hipStream_t stream) {
    const float* x   = (const float*)d_in[0];
    float*       out = (float*)d_out;
    uint4*       xfq = (uint4*)d_ws;     // 180*512*16 = 1,474,560 bytes

    ramp_filter_kernel<<<N_ANG * 2, 512, 0, stream>>>(x, xfq);
    backproj_kernel<<<1024, 128, 0, stream>>>(xfq, out);
}